// Round 8
// baseline (282.189 us; speedup 1.0000x reference)
//
#include <hip/hip_runtime.h>
#include <math.h>

#define Q 256
#define H 256
#define ATTN_K 64
#define CAP 4096
#define HBINS 4096        // 13-bit order-key (sign+exp+4 mantissa), positives only
#define NREP 8

typedef float f4 __attribute__((ext_vector_type(4)));

__device__ __forceinline__ unsigned f2k(float f) {
    unsigned u = __float_as_uint(f);
    return u ^ ((u & 0x80000000u) ? 0xFFFFFFFFu : 0x80000000u);
}

// ============ kernel 0: zero hist replicas + state, GRU gate dots ============
// state: [1]=cand count [2]=arrive
__global__ __launch_bounds__(256) void k_prep(const float* __restrict__ question,
                                              const float* __restrict__ score,
                                              const float* __restrict__ hs,
                                              const float* __restrict__ W_ih,
                                              const float* __restrict__ W_hh,
                                              const float* __restrict__ b_ih,
                                              const float* __restrict__ b_hh,
                                              float* __restrict__ gx, float* __restrict__ gh,
                                              unsigned* __restrict__ hist,
                                              unsigned* __restrict__ state, int N) {
    const int t = threadIdx.x;
    const int b = blockIdx.x;
    const int gid = b * 256 + t;
    if (gid < NREP * HBINS) hist[gid] = 0u;
    if (gid < 16) state[gid] = 0u;

    const int lane = t & 63;
    const int o = b * 4 + (t >> 6);          // 192 blocks cover o in [0,768)
    if (o >= 3 * H) return;
    const int off = (score[0] >= 0.5f) ? 0 : Q;   // only one half of x is nonzero
    const float4 q = *reinterpret_cast<const float4*>(question + lane * 4);
    const float4 h = *reinterpret_cast<const float4*>(hs + (size_t)(N - 1) * H + lane * 4);
    const float4 wx = *reinterpret_cast<const float4*>(W_ih + (size_t)o * (2 * Q) + off + lane * 4);
    const float4 wh = *reinterpret_cast<const float4*>(W_hh + (size_t)o * H + lane * 4);
    float px = wx.x * q.x + wx.y * q.y + wx.z * q.z + wx.w * q.w;
    float ph = wh.x * h.x + wh.y * h.y + wh.z * h.z + wh.w * h.w;
#pragma unroll
    for (int d = 32; d > 0; d >>= 1) {
        px += __shfl_xor(px, d, 64);
        ph += __shfl_xor(ph, d, 64);
    }
    if (lane == 0) {
        gx[o] = px + b_ih[o];
        gh[o] = ph + b_hh[o];
    }
}

// ============ kernel 1: alpha matvec, BLOCK-LINEAR front (fill-isomorphic reads) ============
// Thread gtid reads float4 at linear offset gtid + f*GT. Since GT % 64 == 0, the
// column group (4*gtid)&255 == lane*4 is invariant: q stays in 4 registers.
// One wave == one contiguous 1KB row per front; full-wave butterfly reduces it.
__global__ __launch_bounds__(256) void k_main(const float* __restrict__ questions,
                                              const float* __restrict__ question,
                                              float* __restrict__ alpha, int N) {
    const int t = threadIdx.x;
    const int lane = t & 63;
    const size_t gtid = (size_t)blockIdx.x * 256 + t;
    const size_t GT = (size_t)gridDim.x * 256;        // float4 lanes per front
    const int rowsPerFront = (int)(GT >> 6);          // 8192 at grid 2048x256
    const int wv = (int)(gtid >> 6);                  // wave id == row within front
    const float4 qv = *reinterpret_cast<const float4*>(question + lane * 4);
    const int NF = N / rowsPerFront;

    const f4* src = reinterpret_cast<const f4*>(questions) + gtid;
    int f = 0;
    for (; f + 4 <= NF; f += 4) {
        f4 x0 = __builtin_nontemporal_load(src + 0 * GT);
        f4 x1 = __builtin_nontemporal_load(src + 1 * GT);
        f4 x2 = __builtin_nontemporal_load(src + 2 * GT);
        f4 x3 = __builtin_nontemporal_load(src + 3 * GT);
        src += 4 * GT;
        float s0 = fmaf(x0.x, qv.x, fmaf(x0.y, qv.y, fmaf(x0.z, qv.z, x0.w * qv.w)));
        float s1 = fmaf(x1.x, qv.x, fmaf(x1.y, qv.y, fmaf(x1.z, qv.z, x1.w * qv.w)));
        float s2 = fmaf(x2.x, qv.x, fmaf(x2.y, qv.y, fmaf(x2.z, qv.z, x2.w * qv.w)));
        float s3 = fmaf(x3.x, qv.x, fmaf(x3.y, qv.y, fmaf(x3.z, qv.z, x3.w * qv.w)));
#pragma unroll
        for (int d = 1; d < 64; d <<= 1) {
            s0 += __shfl_xor(s0, d, 64);
            s1 += __shfl_xor(s1, d, 64);
            s2 += __shfl_xor(s2, d, 64);
            s3 += __shfl_xor(s3, d, 64);
        }
        if (lane == 0) {
            const int r = f * rowsPerFront + wv;
            alpha[r]                    = s0;
            alpha[r + rowsPerFront]     = s1;
            alpha[r + 2 * rowsPerFront] = s2;
            alpha[r + 3 * rowsPerFront] = s3;
        }
    }
    for (; f < NF; ++f) {
        f4 x = __builtin_nontemporal_load(src);
        src += GT;
        float s = fmaf(x.x, qv.x, fmaf(x.y, qv.y, fmaf(x.z, qv.z, x.w * qv.w)));
#pragma unroll
        for (int d = 1; d < 64; d <<= 1) s += __shfl_xor(s, d, 64);
        if (lane == 0) alpha[f * rowsPerFront + wv] = s;
    }
    // tail rows (N % rowsPerFront): one row per wave, same contiguous-1KB shape
    for (int r = NF * rowsPerFront + wv; r < N; r += rowsPerFront) {
        const f4* rowp = reinterpret_cast<const f4*>(questions + (size_t)r * Q) + lane;
        f4 x = __builtin_nontemporal_load(rowp);
        float s = fmaf(x.x, qv.x, fmaf(x.y, qv.y, fmaf(x.z, qv.z, x.w * qv.w)));
#pragma unroll
        for (int d = 1; d < 64; d <<= 1) s += __shfl_xor(s, d, 64);
        if (lane == 0) alpha[r] = s;
    }
}

// ============ kernel 2: LDS histogram of alpha -> 8 global replicas ============
__global__ __launch_bounds__(1024) void k_hist(const float* __restrict__ alpha,
                                               unsigned* __restrict__ hist, int N) {
    __shared__ unsigned hb[HBINS];
    const int t = threadIdx.x;
#pragma unroll
    for (int j = 0; j < HBINS / 1024; ++j) hb[t + j * 1024] = 0u;
    __syncthreads();

    const int n4 = N >> 2;
    const int stride = gridDim.x * blockDim.x;
    const float4* a4 = reinterpret_cast<const float4*>(alpha);
    for (int i = blockIdx.x * blockDim.x + t; i < n4; i += stride) {
        float4 a = a4[i];
        float v[4] = {a.x, a.y, a.z, a.w};
#pragma unroll
        for (int j = 0; j < 4; ++j) {
            int rel = (int)(f2k(v[j]) >> 19) - 4096;
            if (rel >= 0) atomicAdd(&hb[rel], 1u);
        }
    }
    if (blockIdx.x == 0 && t < (N & 3)) {
        float v = alpha[(n4 << 2) + t];
        int rel = (int)(f2k(v) >> 19) - 4096;
        if (rel >= 0) atomicAdd(&hb[rel], 1u);
    }
    __syncthreads();
    const unsigned rep = (unsigned)(blockIdx.x & (NREP - 1)) << 12;
#pragma unroll
    for (int j = 0; j < HBINS / 1024; ++j) {
        unsigned v = hb[t + j * 1024];
        if (v) atomicAdd(&hist[rep + t + j * 1024], v);
    }
}

// ============ kernel 3: redundant scan -> collect -> last block head ============
__global__ __launch_bounds__(256) void k_select(const float* __restrict__ alpha,
                                                const float* __restrict__ question,
                                                const float* __restrict__ hs,
                                                const float* __restrict__ W_score,
                                                const float* __restrict__ b_score,
                                                const unsigned* __restrict__ hist,
                                                unsigned* __restrict__ state,
                                                float* __restrict__ cval, int* __restrict__ cidx,
                                                const float* __restrict__ gx,
                                                const float* __restrict__ gh,
                                                float* __restrict__ out, int N) {
    __shared__ float lv[CAP];
    __shared__ int li[CAP];
    __shared__ float sw[ATTN_K];
    __shared__ int si[ATTN_K];
    __shared__ float red[256];
    __shared__ unsigned wsum[4];
    __shared__ int tau_sh;
    __shared__ int last_sh;
    const int t = threadIdx.x;
    const int lane = t & 63;
    const int w = t >> 6;

    // ---- redundant per-block scan of the 8 hist replicas (no cross-block sync) ----
    unsigned c[16];
    {
        const int base16 = 4080 - 16 * t;     // thread t covers bins [base16, base16+15]
#pragma unroll
        for (int g = 0; g < 16; ++g) c[g] = 0u;
#pragma unroll
        for (int r = 0; r < NREP; ++r) {
            const uint4* h4 = reinterpret_cast<const uint4*>(hist + (r << 12) + base16);
#pragma unroll
            for (int k = 0; k < 4; ++k) {
                uint4 v = h4[k];
                c[4 * k + 0] += v.x; c[4 * k + 1] += v.y;
                c[4 * k + 2] += v.z; c[4 * k + 3] += v.w;
            }
        }
    }
    unsigned tsum = 0;
#pragma unroll
    for (int g = 0; g < 16; ++g) tsum += c[g];
    unsigned cum = tsum;                       // inclusive prefix, t ascending = keys descending
#pragma unroll
    for (int d = 1; d < 64; d <<= 1) {
        unsigned y = __shfl_up(cum, d, 64);
        if (lane >= d) cum += y;
    }
    if (lane == 63) wsum[w] = cum;
    __syncthreads();
    {
        unsigned add = 0;
        for (int i = 0; i < w; ++i) add += wsum[i];
        cum += add;
    }
    const unsigned before = cum - tsum;
    if (cum >= (unsigned)ATTN_K && before < (unsigned)ATTN_K) {
        unsigned acc = before;
        int taub = 4080 - 16 * t;
        for (int g = 15; g >= 0; --g) {
            acc += c[g];
            if (acc >= (unsigned)ATTN_K) { taub = 4080 - 16 * t + g; break; }
        }
        tau_sh = taub;
    }
    if (t == 255 && cum < (unsigned)ATTN_K) tau_sh = 0;   // degenerate fallback
    __syncthreads();
    const int tau = tau_sh;

    // ---- collect candidates with rel-key >= tau ----
    {
        const int n4 = N >> 2;
        const int stride = gridDim.x * blockDim.x;
        const float4* a4 = reinterpret_cast<const float4*>(alpha);
        for (int i = blockIdx.x * blockDim.x + t; i < n4; i += stride) {
            float4 a = a4[i];
            float v[4] = {a.x, a.y, a.z, a.w};
#pragma unroll
            for (int j = 0; j < 4; ++j) {
                if ((int)(f2k(v[j]) >> 19) - 4096 >= tau) {
                    unsigned p = atomicAdd(&state[1], 1u);
                    if (p < CAP) { cval[p] = v[j]; cidx[p] = i * 4 + j; }
                }
            }
        }
        if (blockIdx.x == 0 && t < (N & 3)) {
            const int idx = (n4 << 2) + t;
            float v = alpha[idx];
            if ((int)(f2k(v) >> 19) - 4096 >= tau) {
                unsigned p = atomicAdd(&state[1], 1u);
                if (p < CAP) { cval[p] = v; cidx[p] = idx; }
            }
        }
    }

    // ---- arrive; last block does the head ----
    if (t == 0) {
        __threadfence();
        last_sh = (atomicAdd(&state[2], 1u) == gridDim.x - 1) ? 1 : 0;
    }
    __syncthreads();
    if (!last_sh) return;
    __threadfence();

    const int C = min((int)state[1], CAP);
    for (int i = t; i < C; i += 256) { lv[i] = cval[i]; li[i] = cidx[i]; }
    __syncthreads();

    // exact top-64 by wave 0; ties -> lowest index (matches lax.top_k)
    if (t < 64) {
        for (int k = 0; k < ATTN_K; ++k) {
            float bv = -INFINITY;
            int bi = 0x7fffffff;
            int bp = -1;
            for (int i = t; i < C; i += 64) {
                float v = lv[i];
                int id = li[i];
                if (v > bv || (v == bv && id < bi)) { bv = v; bi = id; bp = i; }
            }
#pragma unroll
            for (int d = 32; d > 0; d >>= 1) {
                float ov = __shfl_xor(bv, d, 64);
                int oi = __shfl_xor(bi, d, 64);
                int op = __shfl_xor(bp, d, 64);
                if (ov > bv || (ov == bv && oi < bi)) { bv = ov; bi = oi; bp = op; }
            }
            if (t == 0) {
                sw[k] = bv;
                si[k] = (bi == 0x7fffffff) ? 0 : bi;
                if (bp >= 0) lv[bp] = -INFINITY;
            }
        }
        float m = sw[0];
        float e = expf(sw[t] - m);
        float ssum = e;
#pragma unroll
        for (int d = 32; d > 0; d >>= 1) ssum += __shfl_xor(ssum, d, 64);
        sw[t] = e / ssum;
    }
    __syncthreads();

    // attn_h[j]
    float aj = 0.f;
    for (int k = 0; k < ATTN_K; ++k) {
        aj = fmaf(sw[k], hs[(size_t)si[k] * H + t], aj);
    }

    // pred
    red[t] = W_score[t] * question[t] + W_score[Q + t] * aj;
    __syncthreads();
    for (int d = 128; d > 0; d >>= 1) {
        if (t < d) red[t] += red[t + d];
        __syncthreads();
    }
    if (t == 0) out[0] = red[0] + b_score[0];

    // GRU combine
    {
        float xr = gx[t], xz = gx[H + t], xn = gx[2 * H + t];
        float hr = gh[t], hz = gh[H + t], hn = gh[2 * H + t];
        float r = 1.f / (1.f + expf(-(xr + hr)));
        float z = 1.f / (1.f + expf(-(xz + hz)));
        float n = tanhf(xn + r * hn);
        float hprev = hs[(size_t)(N - 1) * H + t];
        out[1 + t] = (1.f - z) * n + z * hprev;
    }
}

extern "C" void kernel_launch(void* const* d_in, const int* in_sizes, int n_in,
                              void* d_out, int out_size, void* d_ws, size_t ws_size,
                              hipStream_t stream) {
    const float* question = (const float*)d_in[0];
    const float* score    = (const float*)d_in[1];
    const float* questions= (const float*)d_in[2];
    const float* hs       = (const float*)d_in[3];
    const float* W_score  = (const float*)d_in[4];
    const float* b_score  = (const float*)d_in[5];
    const float* W_ih     = (const float*)d_in[6];
    const float* W_hh     = (const float*)d_in[7];
    const float* b_ih     = (const float*)d_in[8];
    const float* b_hh     = (const float*)d_in[9];
    const int N = in_sizes[2] / Q;
    float* out = (float*)d_out;

    char* ws = (char*)d_ws;
    size_t off = 0;
    float* alpha = (float*)(ws + off); off += (size_t)N * sizeof(float);
    off = (off + 255) & ~(size_t)255;
    unsigned* hist = (unsigned*)(ws + off); off += (size_t)NREP * HBINS * sizeof(unsigned);
    unsigned* state = (unsigned*)(ws + off); off += 256;
    float* cval = (float*)(ws + off); off += (size_t)CAP * sizeof(float);
    int* cidx = (int*)(ws + off); off += (size_t)CAP * sizeof(int);
    float* gx = (float*)(ws + off); off += 3 * H * sizeof(float);
    float* gh = (float*)(ws + off); off += 3 * H * sizeof(float);

    k_prep<<<192, 256, 0, stream>>>(question, score, hs, W_ih, W_hh, b_ih, b_hh,
                                    gx, gh, hist, state, N);
    k_main<<<2048, 256, 0, stream>>>(questions, question, alpha, N);
    k_hist<<<256, 1024, 0, stream>>>(alpha, hist, N);
    k_select<<<512, 256, 0, stream>>>(alpha, question, hs, W_score, b_score, hist,
                                      state, cval, cidx, gx, gh, out, N);
}

// Round 9
// 237.848 us; speedup vs baseline: 1.1864x; 1.1864x over previous
//
#include <hip/hip_runtime.h>
#include <math.h>

#define Q 256
#define H 256
#define ATTN_K 64
#define CAP 4096
#define HBINS 4096        // 13-bit order-key (sign+exp+4 mantissa), positives only
#define NREP 8

typedef float f4 __attribute__((ext_vector_type(4)));

__device__ __forceinline__ unsigned f2k(float f) {
    unsigned u = __float_as_uint(f);
    return u ^ ((u & 0x80000000u) ? 0xFFFFFFFFu : 0x80000000u);
}

// ============ kernel 1: init + GRU gate dots + alpha matvec (R4-measured body) ============
// state: [1]=cand count [2]=hist arrive [3]=collect arrive
__global__ __launch_bounds__(256) void k_main(const float* __restrict__ questions,
                                              const float* __restrict__ question,
                                              const float* __restrict__ score,
                                              const float* __restrict__ hs,
                                              const float* __restrict__ W_ih,
                                              const float* __restrict__ W_hh,
                                              const float* __restrict__ b_ih,
                                              const float* __restrict__ b_hh,
                                              float* __restrict__ gx, float* __restrict__ gh,
                                              unsigned* __restrict__ hist,
                                              unsigned* __restrict__ state,
                                              float* __restrict__ alpha, int N) {
    const int t = threadIdx.x;
    const int b = blockIdx.x;
    if (b < NREP * HBINS / 256) hist[b * 256 + t] = 0u;
    if (b == 128 && t < 16) state[t] = 0u;

    const int lane = t & 63;
    const int wid = b * 4 + (t >> 6);

    // ---- GRU gate dots: first 768 waves, one output row each ----
    if (wid < 3 * H) {
        const int o = wid;
        const int off = (score[0] >= 0.5f) ? 0 : Q;   // only one half of x is nonzero
        const float4 q = *reinterpret_cast<const float4*>(question + lane * 4);
        const float4 h = *reinterpret_cast<const float4*>(hs + (size_t)(N - 1) * H + lane * 4);
        const float4 wx = *reinterpret_cast<const float4*>(W_ih + (size_t)o * (2 * Q) + off + lane * 4);
        const float4 wh = *reinterpret_cast<const float4*>(W_hh + (size_t)o * H + lane * 4);
        float px = wx.x * q.x + wx.y * q.y + wx.z * q.z + wx.w * q.w;
        float ph = wh.x * h.x + wh.y * h.y + wh.z * h.z + wh.w * h.w;
#pragma unroll
        for (int d = 32; d > 0; d >>= 1) {
            px += __shfl_xor(px, d, 64);
            ph += __shfl_xor(ph, d, 64);
        }
        if (lane == 0) {
            gx[o] = px + b_ih[o];
            gh[o] = ph + b_hh[o];
        }
    }

    // ---- alpha: 16 lanes/row, 8 rows per wave-iteration, nontemporal streams ----
    const int sub = lane & 15;
    const int rg  = lane >> 4;
    const int nw  = (gridDim.x * blockDim.x) >> 6;

    float4 q[4];
#pragma unroll
    for (int j = 0; j < 4; ++j)
        q[j] = *reinterpret_cast<const float4*>(question + j * 64 + sub * 4);

    const size_t stepRows = (size_t)nw * 8;
    const float* baseA = questions + ((size_t)wid * 8 + rg) * Q + sub * 4;
    for (size_t r0 = (size_t)wid * 8; r0 < (size_t)N; r0 += stepRows, baseA += stepRows * Q) {
        const int rA = (int)r0 + rg;
        const int rB = rA + 4;
        float pA = 0.f, pB = 0.f;
        if (rA < N) {
#pragma unroll
            for (int j = 0; j < 4; ++j) {
                f4 x = __builtin_nontemporal_load(reinterpret_cast<const f4*>(baseA + j * 64));
                pA = fmaf(x.x, q[j].x, fmaf(x.y, q[j].y, fmaf(x.z, q[j].z, fmaf(x.w, q[j].w, pA))));
            }
        }
        if (rB < N) {
#pragma unroll
            for (int j = 0; j < 4; ++j) {
                f4 x = __builtin_nontemporal_load(reinterpret_cast<const f4*>(baseA + 4 * Q + j * 64));
                pB = fmaf(x.x, q[j].x, fmaf(x.y, q[j].y, fmaf(x.z, q[j].z, fmaf(x.w, q[j].w, pB))));
            }
        }
#pragma unroll
        for (int d = 1; d < 16; d <<= 1) {
            pA += __shfl_xor(pA, d, 64);
            pB += __shfl_xor(pB, d, 64);
        }
        if (sub == 0) {
            if (rA < N) alpha[rA] = pA;
            if (rB < N) alpha[rB] = pB;
        }
    }
}

// ============ kernel 2: LDS hist -> 8 replicas; last block sums replicas + scans ============
__global__ __launch_bounds__(1024) void k_histscan(const float* __restrict__ alpha,
                                                   unsigned* __restrict__ hist,
                                                   unsigned* __restrict__ state, int N) {
    __shared__ unsigned hb[HBINS];
    __shared__ unsigned wsum[16];
    __shared__ int last_sh;
    const int t = threadIdx.x;
#pragma unroll
    for (int j = 0; j < HBINS / 1024; ++j) hb[t + j * 1024] = 0u;
    __syncthreads();

    const int n4 = N >> 2;
    const int stride = gridDim.x * blockDim.x;
    const float4* a4 = reinterpret_cast<const float4*>(alpha);
    for (int i = blockIdx.x * blockDim.x + t; i < n4; i += stride) {
        float4 a = a4[i];
        float v[4] = {a.x, a.y, a.z, a.w};
#pragma unroll
        for (int j = 0; j < 4; ++j) {
            int rel = (int)(f2k(v[j]) >> 19) - 4096;
            if (rel >= 0) atomicAdd(&hb[rel], 1u);
        }
    }
    if (blockIdx.x == 0 && t < (N & 3)) {
        float v = alpha[(n4 << 2) + t];
        int rel = (int)(f2k(v) >> 19) - 4096;
        if (rel >= 0) atomicAdd(&hb[rel], 1u);
    }
    __syncthreads();
    const unsigned rep = (unsigned)(blockIdx.x & (NREP - 1)) << 12;
#pragma unroll
    for (int j = 0; j < HBINS / 1024; ++j) {
        unsigned v = hb[t + j * 1024];
        if (v) atomicAdd(&hist[rep + t + j * 1024], v);
    }

    // ---- arrive; last block sums replicas and scans ----
    if (t == 0) {
        __threadfence();
        last_sh = (atomicAdd(&state[2], 1u) == gridDim.x - 1) ? 1 : 0;
    }
    __syncthreads();
    if (!last_sh) return;
    __threadfence();

    // thread t covers 4 descending-key bins [4092-4t .. 4095-4t], summed over replicas
    unsigned c[4] = {0u, 0u, 0u, 0u};
#pragma unroll
    for (int r = 0; r < NREP; ++r) {
        uint4 v = reinterpret_cast<const uint4*>(hist + (r << 12))[1023 - t];
        c[0] += v.x; c[1] += v.y; c[2] += v.z; c[3] += v.w;
    }
    unsigned x = c[0] + c[1] + c[2] + c[3];
    const int lane = t & 63;
    const int w = t >> 6;
#pragma unroll
    for (int d = 1; d < 64; d <<= 1) {
        unsigned y = __shfl_up(x, d, 64);
        if (lane >= d) x += y;
    }
    if (lane == 63) wsum[w] = x;
    __syncthreads();
    if (w == 0 && lane < 16) {
        unsigned s = wsum[lane];
#pragma unroll
        for (int d = 1; d < 16; d <<= 1) {
            unsigned y = __shfl_up(s, d, 64);
            if (lane >= d) s += y;
        }
        wsum[lane] = s;
    }
    __syncthreads();
    unsigned cum = x + ((w > 0) ? wsum[w - 1] : 0u);
    hb[t] = cum;
    __syncthreads();
    if (cum >= (unsigned)ATTN_K && (t == 0 || hb[t - 1] < (unsigned)ATTN_K)) {
        unsigned acc = (t > 0) ? hb[t - 1] : 0u;
        int taub = 4092 - 4 * t;                  // lowest bin of segment
        for (int g = 3; g >= 0; --g) {            // c[3]=highest key in segment
            acc += c[3 - g];                      // descending: c[3],c[2],c[1],c[0]? careful
            // c[k] corresponds to bin (4092-4t)+k; descending order is k=3..0
        }
        // redo explicitly: walk bins high->low
        acc = (t > 0) ? hb[t - 1] : 0u;
        for (int k = 3; k >= 0; --k) {
            acc += c[k];
            if (acc >= (unsigned)ATTN_K) { taub = 4092 - 4 * t + k; break; }
        }
        state[0] = (unsigned)taub;
    }
    if (t == 1023 && cum < (unsigned)ATTN_K) state[0] = 0u;   // degenerate fallback
}

// ============ kernel 3: collect candidates; last block does head ============
__global__ __launch_bounds__(256) void k_collecthead(const float* __restrict__ alpha,
                                                     const float* __restrict__ question,
                                                     const float* __restrict__ hs,
                                                     const float* __restrict__ W_score,
                                                     const float* __restrict__ b_score,
                                                     unsigned* __restrict__ state,
                                                     float* __restrict__ cval, int* __restrict__ cidx,
                                                     const float* __restrict__ gx,
                                                     const float* __restrict__ gh,
                                                     float* __restrict__ out, int N) {
    __shared__ float lv[CAP];
    __shared__ int li[CAP];
    __shared__ float sw[ATTN_K];
    __shared__ int si[ATTN_K];
    __shared__ float red[256];
    __shared__ int last_sh;
    const int t = threadIdx.x;
    const int tau = (int)state[0];

    {
        const int stride = gridDim.x * blockDim.x;
        const int n4 = N >> 2;
        const float4* a4 = reinterpret_cast<const float4*>(alpha);
        for (int i = blockIdx.x * blockDim.x + t; i < n4; i += stride) {
            float4 a = a4[i];
            float v[4] = {a.x, a.y, a.z, a.w};
#pragma unroll
            for (int j = 0; j < 4; ++j) {
                if ((int)(f2k(v[j]) >> 19) - 4096 >= tau) {
                    unsigned p = atomicAdd(&state[1], 1u);
                    if (p < CAP) { cval[p] = v[j]; cidx[p] = i * 4 + j; }
                }
            }
        }
        if (blockIdx.x == 0 && t < (N & 3)) {
            const int idx = (n4 << 2) + t;
            float v = alpha[idx];
            if ((int)(f2k(v) >> 19) - 4096 >= tau) {
                unsigned p = atomicAdd(&state[1], 1u);
                if (p < CAP) { cval[p] = v; cidx[p] = idx; }
            }
        }
    }

    if (t == 0) {
        __threadfence();
        last_sh = (atomicAdd(&state[3], 1u) == gridDim.x - 1) ? 1 : 0;
    }
    __syncthreads();
    if (!last_sh) return;
    __threadfence();

    const int C = min((int)state[1], CAP);
    for (int i = t; i < C; i += 256) { lv[i] = cval[i]; li[i] = cidx[i]; }
    __syncthreads();

    // exact top-64 by wave 0; ties -> lowest index (matches lax.top_k)
    if (t < 64) {
        for (int k = 0; k < ATTN_K; ++k) {
            float bv = -INFINITY;
            int bi = 0x7fffffff;
            int bp = -1;
            for (int i = t; i < C; i += 64) {
                float v = lv[i];
                int id = li[i];
                if (v > bv || (v == bv && id < bi)) { bv = v; bi = id; bp = i; }
            }
#pragma unroll
            for (int d = 32; d > 0; d >>= 1) {
                float ov = __shfl_xor(bv, d, 64);
                int oi = __shfl_xor(bi, d, 64);
                int op = __shfl_xor(bp, d, 64);
                if (ov > bv || (ov == bv && oi < bi)) { bv = ov; bi = oi; bp = op; }
            }
            if (t == 0) {
                sw[k] = bv;
                si[k] = (bi == 0x7fffffff) ? 0 : bi;
                if (bp >= 0) lv[bp] = -INFINITY;
            }
        }
        float m = sw[0];
        float e = expf(sw[t] - m);
        float ssum = e;
#pragma unroll
        for (int d = 32; d > 0; d >>= 1) ssum += __shfl_xor(ssum, d, 64);
        sw[t] = e / ssum;
    }
    __syncthreads();

    // attn_h[j]
    float aj = 0.f;
    for (int k = 0; k < ATTN_K; ++k) {
        aj = fmaf(sw[k], hs[(size_t)si[k] * H + t], aj);
    }

    // pred
    red[t] = W_score[t] * question[t] + W_score[Q + t] * aj;
    __syncthreads();
    for (int d = 128; d > 0; d >>= 1) {
        if (t < d) red[t] += red[t + d];
        __syncthreads();
    }
    if (t == 0) out[0] = red[0] + b_score[0];

    // GRU combine
    {
        float xr = gx[t], xz = gx[H + t], xn = gx[2 * H + t];
        float hr = gh[t], hz = gh[H + t], hn = gh[2 * H + t];
        float r = 1.f / (1.f + expf(-(xr + hr)));
        float z = 1.f / (1.f + expf(-(xz + hz)));
        float n = tanhf(xn + r * hn);
        float hprev = hs[(size_t)(N - 1) * H + t];
        out[1 + t] = (1.f - z) * n + z * hprev;
    }
}

extern "C" void kernel_launch(void* const* d_in, const int* in_sizes, int n_in,
                              void* d_out, int out_size, void* d_ws, size_t ws_size,
                              hipStream_t stream) {
    const float* question = (const float*)d_in[0];
    const float* score    = (const float*)d_in[1];
    const float* questions= (const float*)d_in[2];
    const float* hs       = (const float*)d_in[3];
    const float* W_score  = (const float*)d_in[4];
    const float* b_score  = (const float*)d_in[5];
    const float* W_ih     = (const float*)d_in[6];
    const float* W_hh     = (const float*)d_in[7];
    const float* b_ih     = (const float*)d_in[8];
    const float* b_hh     = (const float*)d_in[9];
    const int N = in_sizes[2] / Q;
    float* out = (float*)d_out;

    char* ws = (char*)d_ws;
    size_t off = 0;
    float* alpha = (float*)(ws + off); off += (size_t)N * sizeof(float);
    off = (off + 255) & ~(size_t)255;
    unsigned* hist = (unsigned*)(ws + off); off += (size_t)NREP * HBINS * sizeof(unsigned);
    unsigned* state = (unsigned*)(ws + off); off += 256;
    float* cval = (float*)(ws + off); off += (size_t)CAP * sizeof(float);
    int* cidx = (int*)(ws + off); off += (size_t)CAP * sizeof(int);
    float* gx = (float*)(ws + off); off += 3 * H * sizeof(float);
    float* gh = (float*)(ws + off); off += 3 * H * sizeof(float);

    k_main<<<2048, 256, 0, stream>>>(questions, question, score, hs, W_ih, W_hh,
                                     b_ih, b_hh, gx, gh, hist, state, alpha, N);
    k_histscan<<<256, 1024, 0, stream>>>(alpha, hist, state, N);
    k_collecthead<<<512, 256, 0, stream>>>(alpha, question, hs, W_score, b_score,
                                           state, cval, cidx, gx, gh, out, N);
}